// Round 8
// baseline (550.352 us; speedup 1.0000x reference)
//
#include <hip/hip_runtime.h>
#include <cstdint>
#include <cstddef>

// ---------------------------------------------------------------------------
// HardInfoNCESyncLoss (B=8192, D=512) — round 8.
// R7 regression diagnosed: (a) launch_bounds(256,5) VGPR 64->48 hurt K-loop,
// (b) 1.2M device-scope atomics = 104MB fabric writes + dependent latency.
// Fix: LDS-atomic slot allocation + plain stores to block-owned regions.
//   candR[64 tiles][8192 rows][6], cntR[64][8192] u8 (coalesced both ways);
//   overflow>6 or total<5 -> exact fallback (FBCAP=16384, unconditional).
// Pipeline: memset(fbCnt) -> nrm -> gemm_topk -> merge -> fallback -> final
// ---------------------------------------------------------------------------

#define TSCALE (1.0f/0.07f)
#define NEG_INF (-__builtin_inff())
#define KD 512
#define NB 8192
#define THR 0.115f
#define SLOTS 6
#define FBCAP 16384

typedef __bf16 bf16_t;
typedef __bf16 bf16x8 __attribute__((ext_vector_type(8)));
typedef float  f32x4  __attribute__((ext_vector_type(4)));

// sorted-descending top5 insert
#define TRY5(v, A0,A1,A2,A3,A4) do { float _v=(v); \
  if (_v > A4) { \
    if (_v > A2) { \
      if (_v > A0)      { A4=A3; A3=A2; A2=A1; A1=A0; A0=_v; } \
      else if (_v > A1) { A4=A3; A3=A2; A2=A1; A1=_v; } \
      else              { A4=A3; A3=A2; A2=_v; } \
    } else { \
      if (_v > A3)      { A4=A3; A3=_v; } \
      else              { A4=_v; } \
    } \
  } } while(0)

static __device__ __forceinline__ void load_lds16(const void* g, void* l) {
  __builtin_amdgcn_global_load_lds(
      (const __attribute__((address_space(1))) void*)g,
      (__attribute__((address_space(3))) void*)(uint32_t)(uintptr_t)l,
      16, 0, 0);
}

// ---------------- kernel 1: L2-normalize, bf16 convert, exact pos ----------
__global__ __launch_bounds__(256)
void nrm_kernel(const float* __restrict__ v, const float* __restrict__ a,
                bf16_t* __restrict__ vb, bf16_t* __restrict__ ab,
                float* __restrict__ pos)
{
  int row  = blockIdx.x * 4 + (threadIdx.x >> 6);
  int lane = threadIdx.x & 63;
  size_t base = (size_t)row * 512 + (size_t)lane * 8;
  float4 v0 = *(const float4*)(v + base);
  float4 v1 = *(const float4*)(v + base + 4);
  float4 a0 = *(const float4*)(a + base);
  float4 a1 = *(const float4*)(a + base + 4);

  float sv = v0.x*v0.x+v0.y*v0.y+v0.z*v0.z+v0.w*v0.w
           + v1.x*v1.x+v1.y*v1.y+v1.z*v1.z+v1.w*v1.w;
  float sa = a0.x*a0.x+a0.y*a0.y+a0.z*a0.z+a0.w*a0.w
           + a1.x*a1.x+a1.y*a1.y+a1.z*a1.z+a1.w*a1.w;
  float sd = v0.x*a0.x+v0.y*a0.y+v0.z*a0.z+v0.w*a0.w
           + v1.x*a1.x+v1.y*a1.y+v1.z*a1.z+v1.w*a1.w;
  #pragma unroll
  for (int m = 32; m; m >>= 1) {
    sv += __shfl_xor(sv, m);
    sa += __shfl_xor(sa, m);
    sd += __shfl_xor(sd, m);
  }
  float iv = 1.0f / fmaxf(sqrtf(sv), 1e-12f);
  float ia = 1.0f / fmaxf(sqrtf(sa), 1e-12f);

  bf16x8 ov, oa;
  ov[0]=(bf16_t)(v0.x*iv); ov[1]=(bf16_t)(v0.y*iv); ov[2]=(bf16_t)(v0.z*iv); ov[3]=(bf16_t)(v0.w*iv);
  ov[4]=(bf16_t)(v1.x*iv); ov[5]=(bf16_t)(v1.y*iv); ov[6]=(bf16_t)(v1.z*iv); ov[7]=(bf16_t)(v1.w*iv);
  oa[0]=(bf16_t)(a0.x*ia); oa[1]=(bf16_t)(a0.y*ia); oa[2]=(bf16_t)(a0.z*ia); oa[3]=(bf16_t)(a0.w*ia);
  oa[4]=(bf16_t)(a1.x*ia); oa[5]=(bf16_t)(a1.y*ia); oa[6]=(bf16_t)(a1.z*ia); oa[7]=(bf16_t)(a1.w*ia);
  *(bf16x8*)(vb + base) = ov;
  *(bf16x8*)(ab + base) = oa;
  if (lane == 0) pos[row] = sd * iv * ia * TSCALE;
}

// ---------------- kernel 2: GEMM tile + LDS-aggregated filter push ---------
// 4096 blocks; XCD x owns a 16x32 (tr,tc) sub-grid (R7: FETCH 240->179MB).
// Block (tr,tc) exclusively owns candR[tc][R0..R0+128][*] and
// candC[tr][C0..C0+128][*]: LDS counters allocate slots, plain stores.
__global__ __launch_bounds__(256, 4)
void gemm_topk(const bf16_t* __restrict__ vb, const bf16_t* __restrict__ ab,
               float* __restrict__ candR, float* __restrict__ candC,
               unsigned char* __restrict__ cntR, unsigned char* __restrict__ cntC)
{
  __shared__ __align__(16) char lds[32768];   // 2 x (A 8K + B 8K)
  int tid  = threadIdx.x;
  int wave = tid >> 6;
  int lane = tid & 63;
  int wr = wave >> 1, wc = wave & 1;
  int r = lane & 15, q = lane >> 4;

  int x     = blockIdx.x & 7;
  int local = blockIdx.x >> 3;
  int tr = (x >> 1) * 16 + (local >> 5);
  int tc = (x & 1) * 32 + (local & 31);
  int R0 = tr << 7, C0 = tc << 7;

  f32x4 acc[4][4];
  #pragma unroll
  for (int mi = 0; mi < 4; ++mi)
    #pragma unroll
    for (int ni = 0; ni < 4; ++ni)
      acc[mi][ni] = (f32x4){0.f,0.f,0.f,0.f};

  auto stage = [&](int k0, int buf) {
    #pragma unroll
    for (int call = 0; call < 2; ++call) {
      int p   = (call*4 + wave)*64 + lane;
      int row = p >> 2;
      int sl  = (p & 3) ^ (row & 3);           // involution swizzle on source
      const bf16_t* ga = vb + (size_t)(R0 + row)*KD + k0 + sl*8;
      const bf16_t* gb = ab + (size_t)(C0 + row)*KD + k0 + sl*8;
      char* la = lds + buf*16384 +        (call*4 + wave)*1024;  // wave-uniform
      char* lb = lds + buf*16384 + 8192 + (call*4 + wave)*1024;
      load_lds16(ga, la);
      load_lds16(gb, lb);
    }
  };

  stage(0, 0);
  __syncthreads();
  #pragma unroll
  for (int ks = 0; ks < 16; ++ks) {            // K = 512
    int cur = ks & 1;
    if (ks < 15) stage((ks+1)*32, cur ^ 1);
    const char* Ab = lds + cur*16384;
    const char* Bb = Ab + 8192;
    int ko = ((q ^ (r & 3)) << 4);
    bf16x8 af[4], bfr[4];
    #pragma unroll
    for (int mi = 0; mi < 4; ++mi)
      af[mi] = *(const bf16x8*)(Ab + (wr*64 + mi*16 + r)*64 + ko);
    #pragma unroll
    for (int ni = 0; ni < 4; ++ni)
      bfr[ni] = *(const bf16x8*)(Bb + (wc*64 + ni*16 + r)*64 + ko);
    #pragma unroll
    for (int mi = 0; mi < 4; ++mi)
      #pragma unroll
      for (int ni = 0; ni < 4; ++ni)
        acc[mi][ni] = __builtin_amdgcn_mfma_f32_16x16x32_bf16(af[mi], bfr[ni], acc[mi][ni], 0, 0, 0);
    __syncthreads();                            // stage(ks+1) landed; reads done
  }

  // ---- diag mask in registers ----
  // row = R0 + wr*64 + mi*16 + q*4 + rg ; col = C0 + wc*64 + ni*16 + r
  if (tr == tc && wr == wc && (r >> 2) == q) {
    #pragma unroll
    for (int mi = 0; mi < 4; ++mi)
      acc[mi][mi][r & 3] = NEG_INF;
  }

  // ---- LDS slot counters (staging LDS is dead after last barrier) ----
  unsigned int* rc = (unsigned int*)lds;        // [128] per-local-row count
  unsigned int* cc = rc + 128;                  // [128] per-local-col count
  if (tid < 256) rc[tid] = 0;
  __syncthreads();

  // ---- threshold filter: LDS-atomic slot, plain global store ----
  #pragma unroll
  for (int mi = 0; mi < 4; ++mi)
    #pragma unroll
    for (int ni = 0; ni < 4; ++ni) {
      f32x4 vq = acc[mi][ni];
      float m4 = fmaxf(fmaxf(vq[0], vq[1]), fmaxf(vq[2], vq[3]));
      if (m4 > THR) {
        int cl = wc*64 + ni*16 + r;
        #pragma unroll
        for (int rg = 0; rg < 4; ++rg) {
          float vv = vq[rg];
          if (vv > THR) {
            int rl = wr*64 + mi*16 + q*4 + rg;
            unsigned int s1 = atomicAdd(&rc[rl], 1u);
            if (s1 < SLOTS) candR[((size_t)tc*NB + R0 + rl)*SLOTS + s1] = vv;
            unsigned int s2 = atomicAdd(&cc[cl], 1u);
            if (s2 < SLOTS) candC[((size_t)tr*NB + C0 + cl)*SLOTS + s2] = vv;
          }
        }
      }
    }
  __syncthreads();

  // ---- write per-(object,tile) counts: block-owned, coalesced ----
  if (tid < 128)
    cntR[(size_t)tc*NB + R0 + tid] = (unsigned char)min(rc[tid], 255u);
  else
    cntC[(size_t)tr*NB + C0 + (tid - 128)] = (unsigned char)min(cc[tid - 128], 255u);
}

// ---------------- kernel 3: per-object top5 + logsumexp --------------------
// 16384 objects (8192 rows + 8192 cols). Coalesced count reads (cnt[t][idx]).
__global__ __launch_bounds__(256)
void merge_kernel(const float* __restrict__ candR, const float* __restrict__ candC,
                  const unsigned char* __restrict__ cntR, const unsigned char* __restrict__ cntC,
                  const float* __restrict__ pos, unsigned int* __restrict__ fbCnt,
                  unsigned int* __restrict__ fbList, float* __restrict__ loss)
{
  int obj = blockIdx.x*256 + threadIdx.x;
  int isCol = obj >> 13;
  int idx = obj & (NB-1);
  const unsigned char* cnt = isCol ? cntC : cntR;
  const float* cand = isCol ? candC : candR;
  float p = pos[idx];                          // pre-scaled by 1/T

  float a0=NEG_INF,a1=NEG_INF,a2=NEG_INF,a3=NEG_INF,a4=NEG_INF;
  int total = 0;
  bool bad = false;
  for (int t = 0; t < 64; ++t) {
    unsigned int c = cnt[(size_t)t*NB + idx];
    total += c;
    if (c > SLOTS) { bad = true; continue; }
    const float* s = cand + ((size_t)t*NB + idx)*SLOTS;
    for (unsigned int j = 0; j < c; ++j) TRY5(s[j], a0,a1,a2,a3,a4);
  }
  if (!bad && total >= 5) {
    float m = fmaxf(p, a0*TSCALE);
    float sum = expf(p - m)
              + expf(a0*TSCALE - m) + expf(a1*TSCALE - m) + expf(a2*TSCALE - m)
              + expf(a3*TSCALE - m) + expf(a4*TSCALE - m);
    loss[obj] = m + logf(sum) - p;
  } else {
    unsigned int slot = atomicAdd(fbCnt, 1u);
    if (slot < FBCAP) fbList[slot] = (unsigned int)obj;
    loss[obj] = 0.f;                           // overwritten by fallback
  }
}

// ---------------- kernel 4: exact fallback (expected: zero work) -----------
__global__ __launch_bounds__(256)
void fallback_kernel(const bf16_t* __restrict__ vb, const bf16_t* __restrict__ ab,
                     const float* __restrict__ pos,
                     const unsigned int* __restrict__ fbCnt,
                     const unsigned int* __restrict__ fbList,
                     float* __restrict__ loss)
{
  __shared__ float xrow[512];
  __shared__ float t5[256*5];
  unsigned int n = *fbCnt;
  if (n > FBCAP) n = FBCAP;
  for (unsigned int i = blockIdx.x; i < n; i += gridDim.x) {
    unsigned int obj = fbList[i];
    int dir = obj >> 13;
    int idx = obj & (NB-1);
    const bf16_t* X = dir ? ab : vb;           // col j of sim = row j of a v^T
    const bf16_t* Y = dir ? vb : ab;
    __syncthreads();
    for (int j = threadIdx.x; j < 512; j += 256)
      xrow[j] = (float)X[(size_t)idx*KD + j];
    __syncthreads();
    float a0=NEG_INF,a1=NEG_INF,a2=NEG_INF,a3=NEG_INF,a4=NEG_INF;
    for (int cc2 = 0; cc2 < 32; ++cc2) {
      int cidx = cc2*256 + threadIdx.x;
      if (cidx == idx) continue;
      float d = 0.f;
      for (int k = 0; k < 512; k += 8) {
        bf16x8 y = *(const bf16x8*)(Y + (size_t)cidx*KD + k);
        #pragma unroll
        for (int e = 0; e < 8; ++e) d += xrow[k+e] * (float)y[e];
      }
      TRY5(d, a0,a1,a2,a3,a4);
    }
    float* dst = t5 + (size_t)threadIdx.x*5;
    dst[0]=a0; dst[1]=a1; dst[2]=a2; dst[3]=a3; dst[4]=a4;
    __syncthreads();
    if (threadIdx.x == 0) {
      float m0=NEG_INF,m1=NEG_INF,m2=NEG_INF,m3=NEG_INF,m4=NEG_INF;
      for (int j = 0; j < 256*5; ++j) TRY5(t5[j], m0,m1,m2,m3,m4);
      float p = pos[idx];
      float m = fmaxf(p, m0*TSCALE);
      float sum = expf(p - m)
                + expf(m0*TSCALE - m) + expf(m1*TSCALE - m) + expf(m2*TSCALE - m)
                + expf(m3*TSCALE - m) + expf(m4*TSCALE - m);
      loss[obj] = m + logf(sum) - p;
    }
    __syncthreads();
  }
}

// ---------------- kernel 5: final scalar (sum 16384 losses) ----------------
__global__ __launch_bounds__(1024)
void final_kernel(const float* __restrict__ loss, float* __restrict__ out)
{
  int tid = threadIdx.x;
  float v = 0.f;
  #pragma unroll
  for (int j = 0; j < 16; ++j) v += loss[j*1024 + tid];
  #pragma unroll
  for (int m = 32; m; m >>= 1) v += __shfl_xor(v, m);
  __shared__ float wsum[16];
  if ((tid & 63) == 0) wsum[tid >> 6] = v;
  __syncthreads();
  if (tid == 0) {
    float t = 0.f;
    #pragma unroll
    for (int j = 0; j < 16; ++j) t += wsum[j];
    out[0] = 0.5f * t / 8192.0f;
  }
}

// ---------------------------------------------------------------------------
extern "C" void kernel_launch(void* const* d_in, const int* in_sizes, int n_in,
                              void* d_out, int out_size, void* d_ws, size_t ws_size,
                              hipStream_t stream)
{
  const float* v = (const float*)d_in[0];
  const float* a = (const float*)d_in[1];
  char* ws = (char*)d_ws;

  constexpr size_t OFF_AB   = 8ull*1024*1024;
  constexpr size_t OFF_POS  = 16ull*1024*1024;          // 32 KB
  constexpr size_t OFF_CNTR = OFF_POS + 64*1024;        // 64*8192 u8 = 512 KB
  constexpr size_t OFF_CNTC = OFF_CNTR + 512*1024;      // 512 KB
  constexpr size_t OFF_FBC  = OFF_CNTC + 512*1024;      // 4 B
  constexpr size_t OFF_FBL  = OFF_FBC + 256;            // 16384 u32 = 64 KB
  constexpr size_t OFF_LOSS = OFF_FBL + 64*1024;        // 16384 f32 = 64 KB
  constexpr size_t OFF_CR   = 24ull*1024*1024;          // 64*8192*6*4 = 12.6 MB
  constexpr size_t OFF_CC   = 40ull*1024*1024;          // 12.6 MB

  bf16_t* vb   = (bf16_t*)ws;
  bf16_t* ab   = (bf16_t*)(ws + OFF_AB);
  float* pos   = (float*)(ws + OFF_POS);
  unsigned char* cntR = (unsigned char*)(ws + OFF_CNTR);
  unsigned char* cntC = (unsigned char*)(ws + OFF_CNTC);
  unsigned int* fbCnt  = (unsigned int*)(ws + OFF_FBC);
  unsigned int* fbList = (unsigned int*)(ws + OFF_FBL);
  float* loss  = (float*)(ws + OFF_LOSS);
  float* candR = (float*)(ws + OFF_CR);
  float* candC = (float*)(ws + OFF_CC);
  float* out   = (float*)d_out;

  hipMemsetAsync(ws + OFF_FBC, 0, 256, stream);        // fbCnt only
  hipLaunchKernelGGL(nrm_kernel,      dim3(2048), dim3(256),  0, stream, v, a, vb, ab, pos);
  hipLaunchKernelGGL(gemm_topk,       dim3(4096), dim3(256),  0, stream, vb, ab, candR, candC, cntR, cntC);
  hipLaunchKernelGGL(merge_kernel,    dim3(64),   dim3(256),  0, stream, candR, candC, cntR, cntC, pos, fbCnt, fbList, loss);
  hipLaunchKernelGGL(fallback_kernel, dim3(64),   dim3(256),  0, stream, vb, ab, pos, fbCnt, fbList, loss);
  hipLaunchKernelGGL(final_kernel,    dim3(1),    dim3(1024), 0, stream, loss, out);
}

// Round 10
// 236.312 us; speedup vs baseline: 2.3289x; 2.3289x over previous
//
#include <hip/hip_runtime.h>
#include <cstdint>
#include <cstddef>

// ---------------------------------------------------------------------------
// HardInfoNCESyncLoss (B=8192, D=512) — round 9 (resubmit; R9 bench was an
// infra timeout, kernel never ran).
// R8 failure localized: per-TILE overflow P(count>6)~3e-6 x 1M tile-rows
// => ~3-4 objects flagged => 320us serial fallback. Fix: SLOTS 6->12
// (Poisson tail P(X>=13) ~ 1e-13/tile-row => expected flags ~1e-7).
// Everything else held from R8: launch_bounds(256,4) (VGPR-64 K-loop),
// LDS-atomic slot alloc + plain block-owned stores, XCD 16x32 sub-grid,
// exact fallback as unconditional backstop.
// Pipeline: memset(fbCnt) -> nrm -> gemm_topk -> merge -> fallback -> final
// ---------------------------------------------------------------------------

#define TSCALE (1.0f/0.07f)
#define NEG_INF (-__builtin_inff())
#define KD 512
#define NB 8192
#define THR 0.115f
#define SLOTS 12
#define FBCAP 16384

typedef __bf16 bf16_t;
typedef __bf16 bf16x8 __attribute__((ext_vector_type(8)));
typedef float  f32x4  __attribute__((ext_vector_type(4)));

// sorted-descending top5 insert
#define TRY5(v, A0,A1,A2,A3,A4) do { float _v=(v); \
  if (_v > A4) { \
    if (_v > A2) { \
      if (_v > A0)      { A4=A3; A3=A2; A2=A1; A1=A0; A0=_v; } \
      else if (_v > A1) { A4=A3; A3=A2; A2=A1; A1=_v; } \
      else              { A4=A3; A3=A2; A2=_v; } \
    } else { \
      if (_v > A3)      { A4=A3; A3=_v; } \
      else              { A4=_v; } \
    } \
  } } while(0)

static __device__ __forceinline__ void load_lds16(const void* g, void* l) {
  __builtin_amdgcn_global_load_lds(
      (const __attribute__((address_space(1))) void*)g,
      (__attribute__((address_space(3))) void*)(uint32_t)(uintptr_t)l,
      16, 0, 0);
}

// ---------------- kernel 1: L2-normalize, bf16 convert, exact pos ----------
__global__ __launch_bounds__(256)
void nrm_kernel(const float* __restrict__ v, const float* __restrict__ a,
                bf16_t* __restrict__ vb, bf16_t* __restrict__ ab,
                float* __restrict__ pos)
{
  int row  = blockIdx.x * 4 + (threadIdx.x >> 6);
  int lane = threadIdx.x & 63;
  size_t base = (size_t)row * 512 + (size_t)lane * 8;
  float4 v0 = *(const float4*)(v + base);
  float4 v1 = *(const float4*)(v + base + 4);
  float4 a0 = *(const float4*)(a + base);
  float4 a1 = *(const float4*)(a + base + 4);

  float sv = v0.x*v0.x+v0.y*v0.y+v0.z*v0.z+v0.w*v0.w
           + v1.x*v1.x+v1.y*v1.y+v1.z*v1.z+v1.w*v1.w;
  float sa = a0.x*a0.x+a0.y*a0.y+a0.z*a0.z+a0.w*a0.w
           + a1.x*a1.x+a1.y*a1.y+a1.z*a1.z+a1.w*a1.w;
  float sd = v0.x*a0.x+v0.y*a0.y+v0.z*a0.z+v0.w*a0.w
           + v1.x*a1.x+v1.y*a1.y+v1.z*a1.z+v1.w*a1.w;
  #pragma unroll
  for (int m = 32; m; m >>= 1) {
    sv += __shfl_xor(sv, m);
    sa += __shfl_xor(sa, m);
    sd += __shfl_xor(sd, m);
  }
  float iv = 1.0f / fmaxf(sqrtf(sv), 1e-12f);
  float ia = 1.0f / fmaxf(sqrtf(sa), 1e-12f);

  bf16x8 ov, oa;
  ov[0]=(bf16_t)(v0.x*iv); ov[1]=(bf16_t)(v0.y*iv); ov[2]=(bf16_t)(v0.z*iv); ov[3]=(bf16_t)(v0.w*iv);
  ov[4]=(bf16_t)(v1.x*iv); ov[5]=(bf16_t)(v1.y*iv); ov[6]=(bf16_t)(v1.z*iv); ov[7]=(bf16_t)(v1.w*iv);
  oa[0]=(bf16_t)(a0.x*ia); oa[1]=(bf16_t)(a0.y*ia); oa[2]=(bf16_t)(a0.z*ia); oa[3]=(bf16_t)(a0.w*ia);
  oa[4]=(bf16_t)(a1.x*ia); oa[5]=(bf16_t)(a1.y*ia); oa[6]=(bf16_t)(a1.z*ia); oa[7]=(bf16_t)(a1.w*ia);
  *(bf16x8*)(vb + base) = ov;
  *(bf16x8*)(ab + base) = oa;
  if (lane == 0) pos[row] = sd * iv * ia * TSCALE;
}

// ---------------- kernel 2: GEMM tile + LDS-aggregated filter push ---------
// 4096 blocks; XCD x owns a 16x32 (tr,tc) sub-grid (FETCH 240->179MB in R7).
// Block (tr,tc) exclusively owns candR[tc][R0..R0+128][*] and
// candC[tr][C0..C0+128][*]: LDS counters allocate slots, plain stores.
__global__ __launch_bounds__(256, 4)
void gemm_topk(const bf16_t* __restrict__ vb, const bf16_t* __restrict__ ab,
               float* __restrict__ candR, float* __restrict__ candC,
               unsigned char* __restrict__ cntR, unsigned char* __restrict__ cntC)
{
  __shared__ __align__(16) char lds[32768];   // 2 x (A 8K + B 8K)
  int tid  = threadIdx.x;
  int wave = tid >> 6;
  int lane = tid & 63;
  int wr = wave >> 1, wc = wave & 1;
  int r = lane & 15, q = lane >> 4;

  int x     = blockIdx.x & 7;
  int local = blockIdx.x >> 3;
  int tr = (x >> 1) * 16 + (local >> 5);
  int tc = (x & 1) * 32 + (local & 31);
  int R0 = tr << 7, C0 = tc << 7;

  f32x4 acc[4][4];
  #pragma unroll
  for (int mi = 0; mi < 4; ++mi)
    #pragma unroll
    for (int ni = 0; ni < 4; ++ni)
      acc[mi][ni] = (f32x4){0.f,0.f,0.f,0.f};

  auto stage = [&](int k0, int buf) {
    #pragma unroll
    for (int call = 0; call < 2; ++call) {
      int p   = (call*4 + wave)*64 + lane;
      int row = p >> 2;
      int sl  = (p & 3) ^ (row & 3);           // involution swizzle on source
      const bf16_t* ga = vb + (size_t)(R0 + row)*KD + k0 + sl*8;
      const bf16_t* gb = ab + (size_t)(C0 + row)*KD + k0 + sl*8;
      char* la = lds + buf*16384 +        (call*4 + wave)*1024;  // wave-uniform
      char* lb = lds + buf*16384 + 8192 + (call*4 + wave)*1024;
      load_lds16(ga, la);
      load_lds16(gb, lb);
    }
  };

  stage(0, 0);
  __syncthreads();
  #pragma unroll
  for (int ks = 0; ks < 16; ++ks) {            // K = 512
    int cur = ks & 1;
    if (ks < 15) stage((ks+1)*32, cur ^ 1);
    const char* Ab = lds + cur*16384;
    const char* Bb = Ab + 8192;
    int ko = ((q ^ (r & 3)) << 4);
    bf16x8 af[4], bfr[4];
    #pragma unroll
    for (int mi = 0; mi < 4; ++mi)
      af[mi] = *(const bf16x8*)(Ab + (wr*64 + mi*16 + r)*64 + ko);
    #pragma unroll
    for (int ni = 0; ni < 4; ++ni)
      bfr[ni] = *(const bf16x8*)(Bb + (wc*64 + ni*16 + r)*64 + ko);
    #pragma unroll
    for (int mi = 0; mi < 4; ++mi)
      #pragma unroll
      for (int ni = 0; ni < 4; ++ni)
        acc[mi][ni] = __builtin_amdgcn_mfma_f32_16x16x32_bf16(af[mi], bfr[ni], acc[mi][ni], 0, 0, 0);
    __syncthreads();                            // stage(ks+1) landed; reads done
  }

  // ---- diag mask in registers ----
  // row = R0 + wr*64 + mi*16 + q*4 + rg ; col = C0 + wc*64 + ni*16 + r
  if (tr == tc && wr == wc && (r >> 2) == q) {
    #pragma unroll
    for (int mi = 0; mi < 4; ++mi)
      acc[mi][mi][r & 3] = NEG_INF;
  }

  // ---- LDS slot counters (staging LDS is dead after last barrier) ----
  unsigned int* rc = (unsigned int*)lds;        // [128] per-local-row count
  unsigned int* cc = rc + 128;                  // [128] per-local-col count
  if (tid < 256) rc[tid] = 0;
  __syncthreads();

  // ---- threshold filter: LDS-atomic slot, plain global store ----
  #pragma unroll
  for (int mi = 0; mi < 4; ++mi)
    #pragma unroll
    for (int ni = 0; ni < 4; ++ni) {
      f32x4 vq = acc[mi][ni];
      float m4 = fmaxf(fmaxf(vq[0], vq[1]), fmaxf(vq[2], vq[3]));
      if (m4 > THR) {
        int cl = wc*64 + ni*16 + r;
        #pragma unroll
        for (int rg = 0; rg < 4; ++rg) {
          float vv = vq[rg];
          if (vv > THR) {
            int rl = wr*64 + mi*16 + q*4 + rg;
            unsigned int s1 = atomicAdd(&rc[rl], 1u);
            if (s1 < SLOTS) candR[((size_t)tc*NB + R0 + rl)*SLOTS + s1] = vv;
            unsigned int s2 = atomicAdd(&cc[cl], 1u);
            if (s2 < SLOTS) candC[((size_t)tr*NB + C0 + cl)*SLOTS + s2] = vv;
          }
        }
      }
    }
  __syncthreads();

  // ---- write per-(object,tile) counts: block-owned, coalesced ----
  if (tid < 128)
    cntR[(size_t)tc*NB + R0 + tid] = (unsigned char)min(rc[tid], 255u);
  else
    cntC[(size_t)tr*NB + C0 + (tid - 128)] = (unsigned char)min(cc[tid - 128], 255u);
}

// ---------------- kernel 3: per-object top5 + logsumexp --------------------
// 16384 objects (8192 rows + 8192 cols). Coalesced count reads (cnt[t][idx]).
__global__ __launch_bounds__(256)
void merge_kernel(const float* __restrict__ candR, const float* __restrict__ candC,
                  const unsigned char* __restrict__ cntR, const unsigned char* __restrict__ cntC,
                  const float* __restrict__ pos, unsigned int* __restrict__ fbCnt,
                  unsigned int* __restrict__ fbList, float* __restrict__ loss)
{
  int obj = blockIdx.x*256 + threadIdx.x;
  int isCol = obj >> 13;
  int idx = obj & (NB-1);
  const unsigned char* cnt = isCol ? cntC : cntR;
  const float* cand = isCol ? candC : candR;
  float p = pos[idx];                          // pre-scaled by 1/T

  float a0=NEG_INF,a1=NEG_INF,a2=NEG_INF,a3=NEG_INF,a4=NEG_INF;
  int total = 0;
  bool bad = false;
  for (int t = 0; t < 64; ++t) {
    unsigned int c = cnt[(size_t)t*NB + idx];
    total += c;
    if (c > SLOTS) { bad = true; continue; }
    const float* s = cand + ((size_t)t*NB + idx)*SLOTS;
    for (unsigned int j = 0; j < c; ++j) TRY5(s[j], a0,a1,a2,a3,a4);
  }
  if (!bad && total >= 5) {
    float m = fmaxf(p, a0*TSCALE);
    float sum = expf(p - m)
              + expf(a0*TSCALE - m) + expf(a1*TSCALE - m) + expf(a2*TSCALE - m)
              + expf(a3*TSCALE - m) + expf(a4*TSCALE - m);
    loss[obj] = m + logf(sum) - p;
  } else {
    unsigned int slot = atomicAdd(fbCnt, 1u);
    if (slot < FBCAP) fbList[slot] = (unsigned int)obj;
    loss[obj] = 0.f;                           // overwritten by fallback
  }
}

// ---------------- kernel 4: exact fallback (expected: zero work) -----------
__global__ __launch_bounds__(256)
void fallback_kernel(const bf16_t* __restrict__ vb, const bf16_t* __restrict__ ab,
                     const float* __restrict__ pos,
                     const unsigned int* __restrict__ fbCnt,
                     const unsigned int* __restrict__ fbList,
                     float* __restrict__ loss)
{
  __shared__ float xrow[512];
  __shared__ float t5[256*5];
  unsigned int n = *fbCnt;
  if (n > FBCAP) n = FBCAP;
  for (unsigned int i = blockIdx.x; i < n; i += gridDim.x) {
    unsigned int obj = fbList[i];
    int dir = obj >> 13;
    int idx = obj & (NB-1);
    const bf16_t* X = dir ? ab : vb;           // col j of sim = row j of a v^T
    const bf16_t* Y = dir ? vb : ab;
    __syncthreads();
    for (int j = threadIdx.x; j < 512; j += 256)
      xrow[j] = (float)X[(size_t)idx*KD + j];
    __syncthreads();
    float a0=NEG_INF,a1=NEG_INF,a2=NEG_INF,a3=NEG_INF,a4=NEG_INF;
    for (int cc2 = 0; cc2 < 32; ++cc2) {
      int cidx = cc2*256 + threadIdx.x;
      if (cidx == idx) continue;
      float d = 0.f;
      for (int k = 0; k < 512; k += 8) {
        bf16x8 y = *(const bf16x8*)(Y + (size_t)cidx*KD + k);
        #pragma unroll
        for (int e = 0; e < 8; ++e) d += xrow[k+e] * (float)y[e];
      }
      TRY5(d, a0,a1,a2,a3,a4);
    }
    float* dst = t5 + (size_t)threadIdx.x*5;
    dst[0]=a0; dst[1]=a1; dst[2]=a2; dst[3]=a3; dst[4]=a4;
    __syncthreads();
    if (threadIdx.x == 0) {
      float m0=NEG_INF,m1=NEG_INF,m2=NEG_INF,m3=NEG_INF,m4=NEG_INF;
      for (int j = 0; j < 256*5; ++j) TRY5(t5[j], m0,m1,m2,m3,m4);
      float p = pos[idx];
      float m = fmaxf(p, m0*TSCALE);
      float sum = expf(p - m)
                + expf(m0*TSCALE - m) + expf(m1*TSCALE - m) + expf(m2*TSCALE - m)
                + expf(m3*TSCALE - m) + expf(m4*TSCALE - m);
      loss[obj] = m + logf(sum) - p;
    }
    __syncthreads();
  }
}

// ---------------- kernel 5: final scalar (sum 16384 losses) ----------------
__global__ __launch_bounds__(1024)
void final_kernel(const float* __restrict__ loss, float* __restrict__ out)
{
  int tid = threadIdx.x;
  float v = 0.f;
  #pragma unroll
  for (int j = 0; j < 16; ++j) v += loss[j*1024 + tid];
  #pragma unroll
  for (int m = 32; m; m >>= 1) v += __shfl_xor(v, m);
  __shared__ float wsum[16];
  if ((tid & 63) == 0) wsum[tid >> 6] = v;
  __syncthreads();
  if (tid == 0) {
    float t = 0.f;
    #pragma unroll
    for (int j = 0; j < 16; ++j) t += wsum[j];
    out[0] = 0.5f * t / 8192.0f;
  }
}

// ---------------------------------------------------------------------------
extern "C" void kernel_launch(void* const* d_in, const int* in_sizes, int n_in,
                              void* d_out, int out_size, void* d_ws, size_t ws_size,
                              hipStream_t stream)
{
  const float* v = (const float*)d_in[0];
  const float* a = (const float*)d_in[1];
  char* ws = (char*)d_ws;

  constexpr size_t OFF_AB   = 8ull*1024*1024;
  constexpr size_t OFF_POS  = 16ull*1024*1024;          // 32 KB
  constexpr size_t OFF_CNTR = OFF_POS + 64*1024;        // 64*8192 u8 = 512 KB
  constexpr size_t OFF_CNTC = OFF_CNTR + 512*1024;      // 512 KB
  constexpr size_t OFF_FBC  = OFF_CNTC + 512*1024;      // 4 B
  constexpr size_t OFF_FBL  = OFF_FBC + 256;            // 16384 u32 = 64 KB
  constexpr size_t OFF_LOSS = OFF_FBL + 64*1024;        // 16384 f32 = 64 KB
  constexpr size_t OFF_CR   = 24ull*1024*1024;          // 64*8192*12*4 = 25.2 MB
  constexpr size_t OFF_CC   = 52ull*1024*1024;          // 25.2 MB

  bf16_t* vb   = (bf16_t*)ws;
  bf16_t* ab   = (bf16_t*)(ws + OFF_AB);
  float* pos   = (float*)(ws + OFF_POS);
  unsigned char* cntR = (unsigned char*)(ws + OFF_CNTR);
  unsigned char* cntC = (unsigned char*)(ws + OFF_CNTC);
  unsigned int* fbCnt  = (unsigned int*)(ws + OFF_FBC);
  unsigned int* fbList = (unsigned int*)(ws + OFF_FBL);
  float* loss  = (float*)(ws + OFF_LOSS);
  float* candR = (float*)(ws + OFF_CR);
  float* candC = (float*)(ws + OFF_CC);
  float* out   = (float*)d_out;

  hipMemsetAsync(ws + OFF_FBC, 0, 256, stream);        // fbCnt only
  hipLaunchKernelGGL(nrm_kernel,      dim3(2048), dim3(256),  0, stream, v, a, vb, ab, pos);
  hipLaunchKernelGGL(gemm_topk,       dim3(4096), dim3(256),  0, stream, vb, ab, candR, candC, cntR, cntC);
  hipLaunchKernelGGL(merge_kernel,    dim3(64),   dim3(256),  0, stream, candR, candC, cntR, cntC, pos, fbCnt, fbList, loss);
  hipLaunchKernelGGL(fallback_kernel, dim3(64),   dim3(256),  0, stream, vb, ab, pos, fbCnt, fbList, loss);
  hipLaunchKernelGGL(final_kernel,    dim3(1),    dim3(1024), 0, stream, loss, out);
}